// Round 2
// 694.597 us; speedup vs baseline: 1.7678x; 1.7678x over previous
//
#include <hip/hip_runtime.h>
#include <math.h>

#define HW 16384   // 128*128

typedef __attribute__((ext_vector_type(8))) short short8;
typedef __attribute__((ext_vector_type(4))) float f32x4;
typedef __attribute__((ext_vector_type(4))) unsigned int u32x4;
typedef __attribute__((ext_vector_type(2))) unsigned int u32x2;

union V4S8 { u32x4 u; short8 s; };

__device__ __forceinline__ float gelu_exact(float x) {
    return 0.5f * x * (1.0f + erff(x * 0.70710678118654752f));
}
__device__ __forceinline__ unsigned short f2bf(float x) {
    unsigned int u = __float_as_uint(x);
    u = (u + 0x7FFFu + ((u >> 16) & 1u)) >> 16;
    return (unsigned short)u;
}
__device__ __forceinline__ unsigned int pack2bf(float lo, float hi) {
    return (unsigned int)f2bf(lo) | ((unsigned int)f2bf(hi) << 16);
}
__device__ __forceinline__ float bf2f(unsigned short s) {
    return __uint_as_float(((unsigned int)s) << 16);
}

// ---------------- weight prep ----------------
__global__ __launch_bounds__(256) void prep_weights(
        const float* __restrict__ ffn_w1, unsigned short* __restrict__ w1b,
        const float* __restrict__ ffn_w2, unsigned short* __restrict__ w2tb,
        const float* __restrict__ fus_w,  unsigned short* __restrict__ fus_wb,
        const float* __restrict__ w_ll, const float* __restrict__ w_lh,
        const float* __restrict__ w_hl, const float* __restrict__ w_hh,
        unsigned short* __restrict__ wb_sub,
        const float* __restrict__ off_w1, unsigned short* __restrict__ wb_off1,
        unsigned short* __restrict__ wb_off1_lo,
        const float* __restrict__ off_w2, float* __restrict__ w4_off2) {
    int gid = blockIdx.x * 256 + threadIdx.x;
    if (gid < 16384) {
        int h = gid >> 6, c = gid & 63;
        w1b[gid] = f2bf(ffn_w1[c * 256 + h]);
    } else if (gid < 32768) {
        int t = gid - 16384;
        int co = t >> 8, h = t & 255;
        w2tb[t] = f2bf(ffn_w2[h * 64 + co]);
    } else if (gid < 49152) {
        int t = gid - 32768;
        fus_wb[t] = f2bf(fus_w[t]);                 // [64 co][256 ci] native
    } else if (gid < 196608) {
        int t = gid - 49152;
        int s = t / 36864, r = t % 36864;
        int ci = r & 63, co = (r >> 6) & 63, tap = r >> 12;
        const float* w = (s == 0) ? w_ll : (s == 1) ? w_lh : (s == 2) ? w_hl : w_hh;
        wb_sub[t] = f2bf(w[co * 576 + ci * 9 + tap]);
    } else if (gid < 215040) {
        int t = gid - 196608;
        int ci = t & 63, co = (t >> 6) & 31, tap = t >> 11;
        float w = off_w1[co * 576 + ci * 9 + tap];
        unsigned short hi = f2bf(w);
        wb_off1[t] = hi;
        wb_off1_lo[t] = f2bf(w - bf2f(hi));
    } else if (gid < 218112) {
        int t = gid - 215040;
        int co = t % 6, q = t / 6;
        int v = q & 3, u = (q >> 2) & 3, ci = q >> 4;
        float sum = 0.0f;
        #pragma unroll
        for (int r = 0; r < 2; ++r)
            #pragma unroll
            for (int s2 = 0; s2 < 2; ++s2) {
                int du = u - r, dv = v - s2;
                if (du >= 0 && du < 3 && dv >= 0 && dv < 3)
                    sum += off_w2[co * 288 + ci * 9 + du * 3 + dv];
            }
        w4_off2[ci * 96 + (u * 4 + v) * 6 + co] = 0.25f * sum;
    }
}

// ---------------- DWT: R -> ll_p [4][64][HW] + hb [3][4][64][HW] ----------------
__global__ __launch_bounds__(256) void dwt_kernel(const float* __restrict__ R,
                                                  float* __restrict__ ll_p,
                                                  float* __restrict__ hb) {
    int gid = blockIdx.x * 256 + threadIdx.x;
    int j = gid & 127;
    int i = (gid >> 7) & 127;
    int c = (gid >> 14) & 63;
    int b = gid >> 20;
    const float* base = R + ((b * 64 + c) * 256 + 2 * i) * 256 + 2 * j;
    float a = base[0], bb = base[1];
    float cc = base[256], dd = base[257];
    size_t po = ((size_t)b * 64 + c) * HW + i * 128 + j;
    ll_p[po]             = (a + bb + cc + dd) * 0.5f;
    hb[po]               = (cc + dd - a - bb) * 0.5f;   // lh
    hb[4194304 + po]     = (bb - a + dd - cc) * 0.5f;   // hl
    hb[2 * 4194304 + po] = (a - bb - cc + dd) * 0.5f;   // hh
}

// ---------------- offset conv 64->32, split-precision bf16 MFMA, K-chunked LDS ----------------
__global__ __launch_bounds__(256) void conv_off_split(const float* __restrict__ R,
                                                      const unsigned short* __restrict__ wh,
                                                      const unsigned short* __restrict__ wl,
                                                      const float* __restrict__ bc,
                                                      float* __restrict__ o1) {
    __shared__ __align__(16) unsigned short sh[324 * 40];  // 25,920 B
    __shared__ __align__(16) unsigned short sl[324 * 40];  // 25,920 B
    int tid = threadIdx.x;
    int w = tid >> 6, lane = tid & 63, q = lane >> 4, m = lane & 15;
    int tx = blockIdx.x & 15, ty = (blockIdx.x >> 4) & 15, b = blockIdx.x >> 8;
    int x0 = tx * 16, y0 = ty * 16;
    const float* inb = R + (size_t)b * (64 * 65536);

    f32x4 acc[4][2];
    #pragma unroll
    for (int pt = 0; pt < 4; ++pt)
        #pragma unroll
        for (int nt = 0; nt < 2; ++nt) {
            float bv = bc[nt * 16 + m];
            acc[pt][nt] = (f32x4){bv, bv, bv, bv};
        }

    for (int kc = 0; kc < 2; ++kc) {
        for (int idx = tid; idx < 324 * 32; idx += 256) {
            int ch = idx / 324, pp = idx - ch * 324;
            int row = pp / 18, col = pp - row * 18;
            int gy = y0 - 1 + row, gx = x0 - 1 + col;
            float v = 0.0f;
            if ((unsigned)gy < 256u && (unsigned)gx < 256u)
                v = inb[(kc * 32 + ch) * 65536 + gy * 256 + gx];
            unsigned short hi = f2bf(v);
            sh[pp * 40 + ch] = hi;
            sl[pp * 40 + ch] = f2bf(v - bf2f(hi));
        }
        __syncthreads();
        for (int tap = 0; tap < 9; ++tap) {
            int ty_ = tap / 3, tx_ = tap - 3 * ty_;
            V4S8 bh0, bh1, bl0, bl1;
            bh0.u = *(const u32x4*)(wh + (tap * 32 + m) * 64 + kc * 32 + q * 8);
            bh1.u = *(const u32x4*)(wh + (tap * 32 + 16 + m) * 64 + kc * 32 + q * 8);
            bl0.u = *(const u32x4*)(wl + (tap * 32 + m) * 64 + kc * 32 + q * 8);
            bl1.u = *(const u32x4*)(wl + (tap * 32 + 16 + m) * 64 + kc * 32 + q * 8);
            #pragma unroll
            for (int pt = 0; pt < 4; ++pt) {
                int off = ((w * 4 + pt + ty_) * 18 + m + tx_) * 40 + q * 8;
                V4S8 ah, al;
                ah.u = *(const u32x4*)(sh + off);
                al.u = *(const u32x4*)(sl + off);
                acc[pt][0] = __builtin_amdgcn_mfma_f32_16x16x32_bf16(ah.s, bh0.s, acc[pt][0], 0, 0, 0);
                acc[pt][1] = __builtin_amdgcn_mfma_f32_16x16x32_bf16(ah.s, bh1.s, acc[pt][1], 0, 0, 0);
                acc[pt][0] = __builtin_amdgcn_mfma_f32_16x16x32_bf16(al.s, bh0.s, acc[pt][0], 0, 0, 0);
                acc[pt][1] = __builtin_amdgcn_mfma_f32_16x16x32_bf16(al.s, bh1.s, acc[pt][1], 0, 0, 0);
                acc[pt][0] = __builtin_amdgcn_mfma_f32_16x16x32_bf16(ah.s, bl0.s, acc[pt][0], 0, 0, 0);
                acc[pt][1] = __builtin_amdgcn_mfma_f32_16x16x32_bf16(ah.s, bl1.s, acc[pt][1], 0, 0, 0);
            }
        }
        __syncthreads();
    }

    float* ob = o1 + (size_t)b * (32 * 65536);
    #pragma unroll
    for (int pt = 0; pt < 4; ++pt) {
        int py = y0 + w * 4 + pt;
        #pragma unroll
        for (int nt = 0; nt < 2; ++nt) {
            int co = nt * 16 + m;
            f32x4 v;
            #pragma unroll
            for (int k = 0; k < 4; ++k) v[k] = gelu_exact(acc[pt][nt][k]);
            *(f32x4*)(ob + co * 65536 + py * 256 + x0 + q * 4) = v;
        }
    }
}

// ---------------- conv2 + pool + tanh (fp32) ----------------
__global__ __launch_bounds__(256) void conv2_pool_tiled(const float* __restrict__ o1,
                                                        const float* __restrict__ w4,
                                                        const float* __restrict__ bias,
                                                        float* __restrict__ disp) {
    constexpr int CH = 2;
    __shared__ float tile[CH * 1156];
    int tid = threadIdx.x;
    int bx = blockIdx.x & 7;
    int by = (blockIdx.x >> 3) & 7;
    int b  = blockIdx.x >> 6;
    int lx = tid & 15, ly = tid >> 4;
    int i = by * 16 + ly, j = bx * 16 + lx;
    int gy0 = by * 32 - 1, gx0 = bx * 32 - 1;
    float acc[6];
    #pragma unroll
    for (int co = 0; co < 6; ++co) acc[co] = 0.0f;
    const float* ip = o1 + (size_t)b * (32 * 65536);
    for (int ci0 = 0; ci0 < 32; ci0 += CH) {
        for (int idx = tid; idx < CH * 1156; idx += 256) {
            int p = idx / 1156, r = idx % 1156;
            int ty = r / 34, tx = r % 34;
            int gy = gy0 + ty, gx = gx0 + tx;
            float v = 0.0f;
            if ((unsigned)gy < 256u && (unsigned)gx < 256u)
                v = ip[(ci0 + p) * 65536 + gy * 256 + gx];
            tile[idx] = v;
        }
        __syncthreads();
        #pragma unroll
        for (int p = 0; p < CH; ++p) {
            const float* wrow = w4 + (ci0 + p) * 96;
            const float* base = tile + p * 1156 + (2 * ly) * 34 + 2 * lx;
            #pragma unroll
            for (int u = 0; u < 4; ++u)
                #pragma unroll
                for (int v = 0; v < 4; ++v) {
                    float val = base[u * 34 + v];
                    const float* wr = wrow + (u * 4 + v) * 6;
                    #pragma unroll
                    for (int co = 0; co < 6; ++co)
                        acc[co] = fmaf(val, wr[co], acc[co]);
                }
        }
        __syncthreads();
    }
    #pragma unroll
    for (int co = 0; co < 6; ++co) {
        float pooled = acc[co] + bias[co];
        disp[(size_t)b * (6 * HW) + co * HW + i * 128 + j] = tanhf(pooled) * 0.25f;
    }
}

// ---------------- FUSED deform + conv3x3 + LN + FFN for ALL 4 subbands ----------------
// grid 1024 = [tile 256][s 4]; block 256 = 4 waves. LDS 45.6 KB -> 3 blocks/CU.
// launch_bounds (256,3): LDS caps at 3 blocks/CU anyway; cap unified VGPR+AGPR at ~168
// so we actually GET 3 waves/SIMD (round-0 version held Ht[16]+znp -> ~280 regs -> 1 wave/SIMD,
// OccupancyPercent 12.0%, fully latency-exposed: 780us at <7% on every pipe).
__global__ __launch_bounds__(256, 3) void subband_fused(
        const float* __restrict__ ll_p,            // [4][64][HW]
        const float* __restrict__ hb,              // [3][4][64][HW]
        const float* __restrict__ disp,            // [4][6][HW]
        const unsigned short* __restrict__ wb_sub, // [4][9][64][64]
        const float* __restrict__ b_ll, const float* __restrict__ b_lh,
        const float* __restrict__ b_hl, const float* __restrict__ b_hh,
        unsigned short* __restrict__ fb,           // [4 s][4 b][64][HW] bf16
        const float* __restrict__ lnw, const float* __restrict__ lnb,
        const unsigned short* __restrict__ w1b, const float* __restrict__ b1,
        const unsigned short* __restrict__ w2tb, const float* __restrict__ b2) {
    __shared__ __align__(16) unsigned short stg[324 * 72];   // 46,656 B; re-carved post-conv
    int tid = threadIdx.x;
    int w = tid >> 6, lane = tid & 63, q = lane >> 4, m = lane & 15;
    int s = blockIdx.x & 3;
    int t = blockIdx.x >> 2;
    int bx = t & 7, by = (t >> 3) & 7, b = t >> 6;
    int x0 = bx * 16, y0 = by * 16;
    const unsigned short* wc = wb_sub + s * 36864;
    const float* bc = (s == 0) ? b_ll : (s == 1) ? b_lh : (s == 2) ? b_hl : b_hh;

    // --- staging: 18x18 halo x 64ch, deform fused for s>0 ---
    if (s == 0) {
        const float* inb = ll_p + (size_t)b * (64 * HW);
        for (int pp = tid; pp < 324; pp += 256) {
            int row = pp / 18, col = pp - row * 18;
            int gy = y0 - 1 + row, gx = x0 - 1 + col;
            bool ok = ((unsigned)gy < 128u) && ((unsigned)gx < 128u);
            const float* src = inb + (ok ? (gy * 128 + gx) : 0);
            #pragma unroll 8
            for (int ch = 0; ch < 64; ch += 2) {
                float v0 = ok ? src[ch * HW] : 0.0f;
                float v1 = ok ? src[(ch + 1) * HW] : 0.0f;
                *(unsigned int*)(stg + pp * 72 + ch) = pack2bf(v0, v1);
            }
        }
    } else {
        const float* sp  = hb + (size_t)((s - 1) * 4 + b) * (64 * HW);
        const float* dpb = disp + (size_t)b * (6 * HW) + (s - 1) * 2 * HW;
        for (int pp = tid; pp < 324; pp += 256) {
            int row = pp / 18, col = pp - row * 18;
            int gy = y0 - 1 + row, gx = x0 - 1 + col;
            bool ok = ((unsigned)gy < 128u) && ((unsigned)gx < 128u);
            int o00 = 0, o01 = 0, o10 = 0, o11 = 0;
            float w00 = 0, w01 = 0, w10 = 0, w11 = 0;
            if (ok) {
                int pix = gy * 128 + gx;
                float dx = dpb[pix], dy = dpb[HW + pix];
                float fx = fmaf((float)gx, 2.0f / 127.0f, -1.0f) + dx;
                float fy = fmaf((float)gy, 2.0f / 127.0f, -1.0f) + dy;
                float ix = (fx + 1.0f) * 0.5f * 127.0f;
                float iy = (fy + 1.0f) * 0.5f * 127.0f;
                ix = fabsf(ix); ix = fmodf(ix, 254.0f); if (ix > 127.0f) ix = 254.0f - ix;
                iy = fabsf(iy); iy = fmodf(iy, 254.0f); if (iy > 127.0f) iy = 254.0f - iy;
                float x0f = floorf(ix), y0f = floorf(iy);
                float wx = ix - x0f, wy = iy - y0f;
                int xa = min(max((int)x0f, 0), 127);
                int xb2 = min(xa + 1, 127);
                int ya = min(max((int)y0f, 0), 127);
                int yb2 = min(ya + 1, 127);
                w00 = (1.0f - wx) * (1.0f - wy); w01 = wx * (1.0f - wy);
                w10 = (1.0f - wx) * wy;          w11 = wx * wy;
                o00 = ya * 128 + xa;  o01 = ya * 128 + xb2;
                o10 = yb2 * 128 + xa; o11 = yb2 * 128 + xb2;
            }
            #pragma unroll 4
            for (int ch = 0; ch < 64; ch += 2) {
                const float* pl = sp + ch * HW;
                const float* pl1 = pl + HW;
                float v0 = w00 * pl[o00] + w01 * pl[o01] + w10 * pl[o10] + w11 * pl[o11];
                float v1 = w00 * pl1[o00] + w01 * pl1[o01] + w10 * pl1[o10] + w11 * pl1[o11];
                *(unsigned int*)(stg + pp * 72 + ch) = pack2bf(v0, v1);
            }
        }
    }
    __syncthreads();

    // --- conv MFMA ---
    f32x4 acc[4][4];
    #pragma unroll
    for (int pt = 0; pt < 4; ++pt)
        #pragma unroll
        for (int nt = 0; nt < 4; ++nt) {
            float bv = bc[nt * 16 + m];
            acc[pt][nt] = (f32x4){bv, bv, bv, bv};
        }
    for (int tap = 0; tap < 9; ++tap) {
        int ty_ = tap / 3, tx_ = tap - 3 * ty_;
        #pragma unroll
        for (int kc = 0; kc < 2; ++kc) {
            V4S8 bf[4];
            #pragma unroll
            for (int nt = 0; nt < 4; ++nt)
                bf[nt].u = *(const u32x4*)(wc + (tap * 64 + nt * 16 + m) * 64 + kc * 32 + q * 8);
            #pragma unroll
            for (int pt = 0; pt < 4; ++pt) {
                V4S8 af;
                af.u = *(const u32x4*)(stg + ((w * 4 + pt + ty_) * 18 + m + tx_) * 72 + kc * 32 + q * 8);
                #pragma unroll
                for (int nt = 0; nt < 4; ++nt)
                    acc[pt][nt] = __builtin_amdgcn_mfma_f32_16x16x32_bf16(af.s, bf[nt].s, acc[pt][nt], 0, 0, 0);
            }
        }
    }

    // --- LN stats (registers + shfl only) ---
    f32x4 sv[4], ssv[4];
    #pragma unroll
    for (int pt = 0; pt < 4; ++pt) {
        f32x4 s_ = acc[pt][0], ss_;
        #pragma unroll
        for (int k = 0; k < 4; ++k) ss_[k] = acc[pt][0][k] * acc[pt][0][k];
        #pragma unroll
        for (int nt = 1; nt < 4; ++nt)
            #pragma unroll
            for (int k = 0; k < 4; ++k) {
                s_[k] += acc[pt][nt][k];
                ss_[k] = fmaf(acc[pt][nt][k], acc[pt][nt][k], ss_[k]);
            }
        sv[pt] = s_; ssv[pt] = ss_;
    }
    #pragma unroll
    for (int msk = 1; msk < 16; msk <<= 1)
        #pragma unroll
        for (int pt = 0; pt < 4; ++pt)
            #pragma unroll
            for (int k = 0; k < 4; ++k) {
                sv[pt][k]  += __shfl_xor(sv[pt][k],  msk);
                ssv[pt][k] += __shfl_xor(ssv[pt][k], msk);
            }

    __syncthreads();   // all conv reads of stg done -> stg re-carved per wave

    // --- zn -> per-wave LDS region (aliases stg) ---
    unsigned short* zw = stg + w * 4608;   // 64 px * 72
    float lwv[4], lbv[4];
    #pragma unroll
    for (int nt = 0; nt < 4; ++nt) { lwv[nt] = lnw[nt * 16 + m]; lbv[nt] = lnb[nt * 16 + m]; }
    #pragma unroll
    for (int pt = 0; pt < 4; ++pt) {
        f32x4 mu, rstd;
        #pragma unroll
        for (int k = 0; k < 4; ++k) {
            mu[k] = sv[pt][k] * (1.0f / 64.0f);
            float var = ssv[pt][k] * (1.0f / 64.0f) - mu[k] * mu[k];
            rstd[k] = rsqrtf(var + 1e-5f);
        }
        #pragma unroll
        for (int nt = 0; nt < 4; ++nt)
            #pragma unroll
            for (int k = 0; k < 4; ++k) {
                float zn = (acc[pt][nt][k] - mu[k]) * rstd[k] * lwv[nt] + lbv[nt];
                zw[(pt * 16 + q * 4 + k) * 72 + nt * 16 + m] = f2bf(zn);
            }
    }

    // --- FFN per 16-px group, STREAMED: no Ht[16] array, no znp[4][2] preload.
    // Per group g: read zn0/zn1 to regs, then reuse the group's OWN zn rows
    // (zw + g*1152, 16 px x 72) as the H chunk buffer: produce 4 ht tiles,
    // immediately consume them as 2 K-slices of the second GEMM. kt order over
    // the 8 K-slices is unchanged -> identical arithmetic to the batched version.
    // DS ops are wave-program-order, so no barrier needed (wave-private region).
    float b2v[4];
    #pragma unroll
    for (int nt = 0; nt < 4; ++nt) b2v[nt] = b2[nt * 16 + m];
    #pragma unroll
    for (int g = 0; g < 4; ++g) {
        unsigned short* zg = zw + g * 1152;
        V4S8 zn0, zn1;
        zn0.u = *(const u32x4*)(zg + m * 72 + q * 8);
        zn1.u = *(const u32x4*)(zg + m * 72 + 32 + q * 8);
        f32x4 F[4];
        #pragma unroll
        for (int nt = 0; nt < 4; ++nt) F[nt] = (f32x4){0.0f, 0.0f, 0.0f, 0.0f};
        #pragma unroll
        for (int hc = 0; hc < 4; ++hc) {
            #pragma unroll
            for (int htl = 0; htl < 4; ++htl) {
                int ht = hc * 4 + htl;
                f32x4 d = {0.0f, 0.0f, 0.0f, 0.0f};
                V4S8 a0, a1;
                a0.u = *(const u32x4*)(w1b + (ht * 16 + m) * 64 + q * 8);
                a1.u = *(const u32x4*)(w1b + (ht * 16 + m) * 64 + 32 + q * 8);
                d = __builtin_amdgcn_mfma_f32_16x16x32_bf16(a0.s, zn0.s, d, 0, 0, 0);
                d = __builtin_amdgcn_mfma_f32_16x16x32_bf16(a1.s, zn1.s, d, 0, 0, 0);
                const f32x4 bv = *(const f32x4*)(b1 + ht * 16 + q * 4);
                u32x2 pk;
                pk[0] = pack2bf(gelu_exact(d[0] + bv[0]), gelu_exact(d[1] + bv[1]));
                pk[1] = pack2bf(gelu_exact(d[2] + bv[2]), gelu_exact(d[3] + bv[3]));
                *(u32x2*)(zg + m * 72 + htl * 16 + q * 4) = pk;
            }
            #pragma unroll
            for (int kt2 = 0; kt2 < 2; ++kt2) {
                int kt = hc * 2 + kt2;
                V4S8 af;
                af.u = *(const u32x4*)(zg + m * 72 + kt2 * 32 + q * 8);
                #pragma unroll
                for (int nt = 0; nt < 4; ++nt) {
                    V4S8 bf_;
                    bf_.u = *(const u32x4*)(w2tb + (nt * 16 + m) * 256 + kt * 32 + q * 8);
                    F[nt] = __builtin_amdgcn_mfma_f32_16x16x32_bf16(af.s, bf_.s, F[nt], 0, 0, 0);
                }
            }
        }
        int py = y0 + w * 4 + g;
        unsigned short* ob = fb + (size_t)((s * 4 + b) * 64) * HW + py * 128 + x0 + q * 4;
        #pragma unroll
        for (int nt = 0; nt < 4; ++nt) {
            int co = nt * 16 + m;
            float r0 = acc[g][nt][0] + F[nt][0] + b2v[nt];
            float r1 = acc[g][nt][1] + F[nt][1] + b2v[nt];
            float r2 = acc[g][nt][2] + F[nt][2] + b2v[nt];
            float r3 = acc[g][nt][3] + F[nt][3] + b2v[nt];
            u32x2 pk;
            pk[0] = pack2bf(r0, r1);
            pk[1] = pack2bf(r2, r3);
            *(u32x2*)(ob + (size_t)co * HW) = pk;
        }
    }
}

// ---------------- FUSED 1x1 fusion conv (K=256) + LN + FFN + residual ----------------
// grid 1024; block 256 = 4 waves x 16 px; LDS 33.8 KB -> 4 blocks/CU.
// Same FFN streaming as subband_fused (Ht[16] removed) + launch_bounds(256,4)
// so the register file allows the full 4 blocks/CU the LDS permits.
__global__ __launch_bounds__(256, 4) void fus_ln_ffn(
        const unsigned short* __restrict__ fb,   // [4 s][4 b][64][HW] bf16
        const unsigned short* __restrict__ fwb,  // [64 co][256 ci] bf16
        const float* __restrict__ fbias,
        float* __restrict__ out,                 // [4][64][HW] fp32
        const float* __restrict__ lnw, const float* __restrict__ lnb,
        const unsigned short* __restrict__ w1b, const float* __restrict__ b1,
        const unsigned short* __restrict__ w2tb, const float* __restrict__ b2) {
    __shared__ __align__(16) unsigned short stgF[64 * 264];  // 33,792 B
    int tid = threadIdx.x;
    int w = tid >> 6, lane = tid & 63, q = lane >> 4, m = lane & 15;
    int gpx = blockIdx.x * 64;
    int b = gpx >> 14;
    int pp0 = gpx & (HW - 1);

    // stage 64 px x 256 ci (bf16 copy, coalesced u32 over px pairs)
    for (int idx = tid; idx < 8192; idx += 256) {
        int ci = idx >> 5, pxp = (idx & 31) << 1;
        int s_ = ci >> 6, c = ci & 63;
        unsigned int v = *(const unsigned int*)(fb + (size_t)((s_ * 4 + b) * 64 + c) * HW + pp0 + pxp);
        stgF[pxp * 264 + ci] = (unsigned short)v;
        stgF[(pxp + 1) * 264 + ci] = (unsigned short)(v >> 16);
    }
    __syncthreads();

    // GEMM: zf[16 px][64 co], K = 256
    f32x4 acc[4];
    #pragma unroll
    for (int nt = 0; nt < 4; ++nt) {
        float bv = fbias[nt * 16 + m];
        acc[nt] = (f32x4){bv, bv, bv, bv};
    }
    #pragma unroll
    for (int kc = 0; kc < 8; ++kc) {
        V4S8 af;
        af.u = *(const u32x4*)(stgF + (w * 16 + m) * 264 + kc * 32 + q * 8);
        #pragma unroll
        for (int nt = 0; nt < 4; ++nt) {
            V4S8 bf_;
            bf_.u = *(const u32x4*)(fwb + (nt * 16 + m) * 256 + kc * 32 + q * 8);
            acc[nt] = __builtin_amdgcn_mfma_f32_16x16x32_bf16(af.s, bf_.s, acc[nt], 0, 0, 0);
        }
    }

    // LN over 64 co
    f32x4 s_ = acc[0], ss_;
    #pragma unroll
    for (int k = 0; k < 4; ++k) ss_[k] = acc[0][k] * acc[0][k];
    #pragma unroll
    for (int nt = 1; nt < 4; ++nt)
        #pragma unroll
        for (int k = 0; k < 4; ++k) {
            s_[k] += acc[nt][k];
            ss_[k] = fmaf(acc[nt][k], acc[nt][k], ss_[k]);
        }
    #pragma unroll
    for (int msk = 1; msk < 16; msk <<= 1)
        #pragma unroll
        for (int k = 0; k < 4; ++k) {
            s_[k]  += __shfl_xor(s_[k],  msk);
            ss_[k] += __shfl_xor(ss_[k], msk);
        }
    f32x4 mu, rstd;
    #pragma unroll
    for (int k = 0; k < 4; ++k) {
        mu[k] = s_[k] * (1.0f / 64.0f);
        float var = ss_[k] * (1.0f / 64.0f) - mu[k] * mu[k];
        rstd[k] = rsqrtf(var + 1e-5f);
    }

    // zn -> wave-private region (aliases own staging rows)
    unsigned short* zw = stgF + w * 4224;
    float lwv[4], lbv[4];
    #pragma unroll
    for (int nt = 0; nt < 4; ++nt) { lwv[nt] = lnw[nt * 16 + m]; lbv[nt] = lnb[nt * 16 + m]; }
    #pragma unroll
    for (int nt = 0; nt < 4; ++nt)
        #pragma unroll
        for (int k = 0; k < 4; ++k) {
            float zn = (acc[nt][k] - mu[k]) * rstd[k] * lwv[nt] + lbv[nt];
            zw[(q * 4 + k) * 72 + nt * 16 + m] = f2bf(zn);
        }
    V4S8 zn0, zn1;
    zn0.u = *(const u32x4*)(zw + m * 72 + q * 8);
    zn1.u = *(const u32x4*)(zw + m * 72 + 32 + q * 8);

    // streamed FFN: H chunk (4 ht = 64 h) reuses the zn rows (zn already in regs)
    f32x4 F[4];
    #pragma unroll
    for (int nt = 0; nt < 4; ++nt) F[nt] = (f32x4){0.0f, 0.0f, 0.0f, 0.0f};
    #pragma unroll
    for (int hc = 0; hc < 4; ++hc) {
        #pragma unroll
        for (int htl = 0; htl < 4; ++htl) {
            int ht = hc * 4 + htl;
            f32x4 d = {0.0f, 0.0f, 0.0f, 0.0f};
            V4S8 a0, a1;
            a0.u = *(const u32x4*)(w1b + (ht * 16 + m) * 64 + q * 8);
            a1.u = *(const u32x4*)(w1b + (ht * 16 + m) * 64 + 32 + q * 8);
            d = __builtin_amdgcn_mfma_f32_16x16x32_bf16(a0.s, zn0.s, d, 0, 0, 0);
            d = __builtin_amdgcn_mfma_f32_16x16x32_bf16(a1.s, zn1.s, d, 0, 0, 0);
            const f32x4 bv = *(const f32x4*)(b1 + ht * 16 + q * 4);
            u32x2 pk;
            pk[0] = pack2bf(gelu_exact(d[0] + bv[0]), gelu_exact(d[1] + bv[1]));
            pk[1] = pack2bf(gelu_exact(d[2] + bv[2]), gelu_exact(d[3] + bv[3]));
            *(u32x2*)(zw + m * 72 + htl * 16 + q * 4) = pk;
        }
        #pragma unroll
        for (int kt2 = 0; kt2 < 2; ++kt2) {
            int kt = hc * 2 + kt2;
            V4S8 af;
            af.u = *(const u32x4*)(zw + m * 72 + kt2 * 32 + q * 8);
            #pragma unroll
            for (int nt = 0; nt < 4; ++nt) {
                V4S8 bf_;
                bf_.u = *(const u32x4*)(w2tb + (nt * 16 + m) * 256 + kt * 32 + q * 8);
                F[nt] = __builtin_amdgcn_mfma_f32_16x16x32_bf16(af.s, bf_.s, F[nt], 0, 0, 0);
            }
        }
    }
    float* ob = out + (size_t)b * (64 * HW);
    #pragma unroll
    for (int nt = 0; nt < 4; ++nt) {
        int co = nt * 16 + m;
        float bias = b2[co];
        f32x4 r;
        #pragma unroll
        for (int k = 0; k < 4; ++k) r[k] = acc[nt][k] + F[nt][k] + bias;
        *(f32x4*)(ob + (size_t)co * HW + pp0 + (w * 16 + q * 4)) = r;
    }
}

extern "C" void kernel_launch(void* const* d_in, const int* in_sizes, int n_in,
                              void* d_out, int out_size, void* d_ws, size_t ws_size,
                              hipStream_t stream) {
    const float* R      = (const float*)d_in[0];
    const float* off_w1 = (const float*)d_in[1];
    const float* off_b1 = (const float*)d_in[2];
    const float* off_w2 = (const float*)d_in[3];
    const float* off_b2 = (const float*)d_in[4];
    const float* w_sub[4] = {(const float*)d_in[5], (const float*)d_in[7],
                             (const float*)d_in[9], (const float*)d_in[11]};
    const float* b_sub[4] = {(const float*)d_in[6], (const float*)d_in[8],
                             (const float*)d_in[10], (const float*)d_in[12]};
    const float* ln_w   = (const float*)d_in[13];
    const float* ln_b   = (const float*)d_in[14];
    const float* ffn_w1 = (const float*)d_in[15];
    const float* ffn_b1 = (const float*)d_in[16];
    const float* ffn_w2 = (const float*)d_in[17];
    const float* ffn_b2 = (const float*)d_in[18];
    const float* fus_w  = (const float*)d_in[19];
    const float* fus_b  = (const float*)d_in[20];

    // ws layout (floats), total 25,678,848 f = 102.7 MB (within round-5 footprint):
    float* ws = (float*)d_ws;
    unsigned short* fbuf = (unsigned short*)ws;          // [4][4][64][HW] bf16 = 8,388,608 f
    float* ll_p = ws + 8388608;                          // 4,194,304 f
    float* o1   = ws + 8388608;                          // 8,388,608 f (dead before ll_p/hb written)
    float* hb   = ws + 12582912;                         // 12,582,912 f (ends 25,165,824)
    float* disp = ws + 25165824;                         // 393,216 f
    float* w4_off2 = ws + 25559040;                      // 3,072 f
    unsigned short* w1b        = (unsigned short*)(ws + 25562112);  // 16,384 s
    unsigned short* w2tb       = (unsigned short*)(ws + 25570304);  // 16,384 s
    unsigned short* fus_wb     = (unsigned short*)(ws + 25578496);  // 16,384 s
    unsigned short* wb_sub     = (unsigned short*)(ws + 25586688);  // 147,456 s
    unsigned short* wb_off1    = (unsigned short*)(ws + 25660416);  // 18,432 s
    unsigned short* wb_off1_lo = (unsigned short*)(ws + 25669632);  // 18,432 s

    prep_weights<<<852, 256, 0, stream>>>(ffn_w1, w1b, ffn_w2, w2tb, fus_w, fus_wb,
                                          w_sub[0], w_sub[1], w_sub[2], w_sub[3], wb_sub,
                                          off_w1, wb_off1, wb_off1_lo, off_w2, w4_off2);
    conv_off_split<<<1024, 256, 0, stream>>>(R, wb_off1, wb_off1_lo, off_b1, o1);
    conv2_pool_tiled<<<256, 256, 0, stream>>>(o1, w4_off2, off_b2, disp);
    dwt_kernel<<<16384, 256, 0, stream>>>(R, ll_p, hb);
    subband_fused<<<1024, 256, 0, stream>>>(ll_p, hb, disp, wb_sub,
                                            b_sub[0], b_sub[1], b_sub[2], b_sub[3], fbuf,
                                            ln_w, ln_b, w1b, ffn_b1, w2tb, ffn_b2);
    fus_ln_ffn<<<1024, 256, 0, stream>>>(fbuf, fus_wb, fus_b, (float*)d_out,
                                         ln_w, ln_b, w1b, ffn_b1, w2tb, ffn_b2);
}